// Round 7
// baseline (21343.755 us; speedup 1.0000x reference)
//
#include <hip/hip_runtime.h>
#include <cmath>
#include <vector>

#define B_SZ 64
#define SEQ 512
#define IN_D 512
#define HID 1024
#define MEM_DIM 8
#define ORD 256
#define MFLAT 2048
#define KTOT 3584            // x(512) | h(1024) | m(2048)
#define NH 128               // H-role blocks
#define NM 64                // M-role blocks
#define NBLK (NH + NM)       // 192
#define BAR_STRIDE 16        // u32 stride per block slot (64B)

typedef __attribute__((ext_vector_type(8))) short short8v;
typedef __attribute__((ext_vector_type(4))) float f32x4;
typedef unsigned long long u64;

// Agent-scope coherent (LLC-direct) 8B accesses — the ONLY coherent path we use.
__device__ inline u64 ald(const void* p) {
  return __hip_atomic_load((const u64*)p, __ATOMIC_RELAXED, __HIP_MEMORY_SCOPE_AGENT);
}
__device__ inline void ast(void* p, u64 v) {
  __hip_atomic_store((u64*)p, v, __ATOMIC_RELAXED, __HIP_MEMORY_SCOPE_AGENT);
}

// RNE float->bf16
__device__ __host__ inline unsigned short f2bf(float f) {
  union { float f; unsigned u; } v; v.f = f;
  unsigned r = v.u + 0x7FFF + ((v.u >> 16) & 1);
  return (unsigned short)(r >> 16);
}
__device__ __host__ inline float bf2f(unsigned short h) {
  union { unsigned u; float f; } v; v.u = ((unsigned)h) << 16;
  return v.f;
}

// ---------------- host-side expm (double, scaling & squaring) ----------------
static void matmul_d(const double* A, const double* B, double* C, int n) {
  for (int i = 0; i < n; ++i) {
    double* Ci = C + (size_t)i * n;
    for (int j = 0; j < n; ++j) Ci[j] = 0.0;
    const double* Ai = A + (size_t)i * n;
    for (int k = 0; k < n; ++k) {
      double a = Ai[k];
      const double* Bk = B + (size_t)k * n;
      for (int j = 0; j < n; ++j) Ci[j] += a * Bk[j];
    }
  }
}

static void compute_AB_host(float* AdT, float* Anat, float* Bd) {
  const int q = ORD, n = ORD + 1;
  const double theta = 512.0;
  std::vector<double> M((size_t)n * n, 0.0);
  for (int i = 0; i < q; ++i) {
    double r = (2.0 * i + 1.0) / theta;
    for (int j = 0; j < q; ++j) {
      double v = (i < j) ? -1.0 : ((((i - j) % 2) == 1) ? 1.0 : -1.0);
      M[(size_t)i * n + j] = v * r;
    }
    M[(size_t)i * n + q] = (((i % 2) == 0) ? 1.0 : -1.0) * r;
  }
  double norm = 0.0;
  for (int j = 0; j < n; ++j) {
    double s = 0.0;
    for (int i = 0; i < n; ++i) s += fabs(M[(size_t)i * n + j]);
    if (s > norm) norm = s;
  }
  int s = 0;
  while (norm > 0.25) { norm *= 0.5; ++s; }
  double sc = ldexp(1.0, -s);
  for (size_t i = 0; i < M.size(); ++i) M[i] *= sc;
  std::vector<double> E((size_t)n * n, 0.0), P = M, T((size_t)n * n);
  for (int i = 0; i < n; ++i) E[(size_t)i * n + i] = 1.0;
  for (size_t i = 0; i < M.size(); ++i) E[i] += M[i];
  for (int k = 2; k <= 30; ++k) {
    matmul_d(P.data(), M.data(), T.data(), n);
    double inv = 1.0 / (double)k, mx = 0.0;
    for (size_t i = 0; i < T.size(); ++i) {
      T[i] *= inv;
      double a = fabs(T[i]);
      if (a > mx) mx = a;
    }
    P.swap(T);
    for (size_t i = 0; i < M.size(); ++i) E[i] += P[i];
    if (mx < 1e-19) break;
  }
  for (int it = 0; it < s; ++it) {
    matmul_d(E.data(), E.data(), T.data(), n);
    E.swap(T);
  }
  for (int p = 0; p < q; ++p) {
    for (int o = 0; o < q; ++o) {
      float v = (float)E[(size_t)p * n + o];
      AdT[(size_t)o * q + p] = v;
      Anat[(size_t)p * q + o] = v;
    }
    Bd[p] = (float)E[(size_t)p * n + q];
  }
}

// ---------------- precompute: WmB[i][d] = sum_p Wm[i][d*256+p] * Bd[p] ----------------
__global__ __launch_bounds__(256) void k_wmb(const float* __restrict__ Wm,
                                             const float* __restrict__ Bd,
                                             float* __restrict__ WmB) {
  int i = blockIdx.x;
  int d = threadIdx.x >> 5, l = threadIdx.x & 31;
  const float* wr = Wm + (size_t)i * MFLAT + d * ORD;
  float acc = 0.f;
  #pragma unroll
  for (int j = 0; j < 8; ++j) { int p = l + 32 * j; acc += wr[p] * Bd[p]; }
  for (int off = 16; off; off >>= 1) acc += __shfl_xor(acc, off);
  if (l == 0) WmB[i * 8 + d] = acc;
}

// ---------------- precompute: Ghi/Glo = split-bf16([Gx | Gh' | Gm']) ----------------
__global__ __launch_bounds__(256) void k_gcat(
    const float* __restrict__ Wx, const float* __restrict__ Wh,
    const float* __restrict__ Wm, const float* __restrict__ Ex,
    const float* __restrict__ Eh, const float* __restrict__ Em,
    const float* __restrict__ Anat, const float* __restrict__ WmB,
    unsigned short* __restrict__ Ghi, unsigned short* __restrict__ Glo) {
  __shared__ float wm[MFLAT];
  __shared__ float wb[8];
  int i = blockIdx.x, tid = threadIdx.x;
  for (int k = tid; k < MFLAT; k += 256) wm[k] = Wm[(size_t)i * MFLAT + k];
  if (tid < 8) wb[tid] = WmB[i * 8 + tid];
  __syncthreads();
  unsigned short* grh = Ghi + (size_t)i * KTOT;
  unsigned short* grl = Glo + (size_t)i * KTOT;
  for (int c = tid; c < KTOT; c += 256) {
    float v;
    if (c < IN_D) {
      v = Wx[(size_t)i * IN_D + c];
      #pragma unroll
      for (int d = 0; d < 8; ++d) v += wb[d] * Ex[(size_t)d * IN_D + c];
    } else if (c < IN_D + HID) {
      int j = c - IN_D;
      v = Wh[(size_t)i * HID + j];
      #pragma unroll
      for (int d = 0; d < 8; ++d) v += wb[d] * Eh[(size_t)d * HID + j];
    } else {
      int cm = c - IN_D - HID;        // (d,o)
      int dd = cm >> 8, o = cm & 255;
      v = 0.f;
      const float* wmd = wm + dd * ORD;
      for (int p = 0; p < ORD; ++p) v += wmd[p] * Anat[(size_t)p * ORD + o];
      #pragma unroll
      for (int d = 0; d < 8; ++d) v += wb[d] * Em[(size_t)d * MFLAT + cm];
    }
    unsigned short hi = f2bf(v);
    grh[c] = hi;
    grl[c] = f2bf(v - bf2f(hi));
  }
}

// ---------------- fence-free device-scope grid barrier ----------------
// All cross-block data moves through agent-scope (LLC-direct) atomics, so no
// cache-maintenance fence is needed. __syncthreads drains vmcnt (stores at LLC)
// before the slot release; per-wave in-order issue orders the post-barrier loads.
__device__ inline void grid_barrier(unsigned* __restrict__ arr,
                                    unsigned* __restrict__ go, unsigned ep) {
  __syncthreads();
  if (blockIdx.x == 0) {
    int tid = threadIdx.x;
    if (tid > 0 && tid < NBLK) {
      while (__hip_atomic_load(&arr[tid * BAR_STRIDE], __ATOMIC_RELAXED,
                               __HIP_MEMORY_SCOPE_AGENT) < ep) {}
    }
    __syncthreads();
    if (tid == 0)
      __hip_atomic_store(go, ep, __ATOMIC_RELAXED, __HIP_MEMORY_SCOPE_AGENT);
  } else {
    if (threadIdx.x == 0) {
      __hip_atomic_store(&arr[blockIdx.x * BAR_STRIDE], ep, __ATOMIC_RELAXED,
                         __HIP_MEMORY_SCOPE_AGENT);
      while (__hip_atomic_load(go, __ATOMIC_RELAXED,
                               __HIP_MEMORY_SCOPE_AGENT) < ep) {}
    }
  }
  __syncthreads();
}

// ---------------- persistent kernel ----------------
// blocks [0,128): H role, 4 waves = 2 tile-waves x 2 K-halves; tile 32b x 16i.
// blocks [128,192): M role, batch b (fixed per block for the whole sequence).
// Cross-block state = ONLY the hi/lo bf16 mirrors (agent atomics). G, AdT, E, x,
// and the per-batch fp32 m master use plain cached loads (L2 stays hot).
__global__ __launch_bounds__(256) void k_persist(
    const float* __restrict__ x, const float* __restrict__ Ex,
    const float* __restrict__ Eh, const float* __restrict__ Em,
    const unsigned short* __restrict__ Ghi, const unsigned short* __restrict__ Glo,
    const float* __restrict__ AdT, const float* __restrict__ Bd,
    unsigned short* __restrict__ sh0, unsigned short* __restrict__ sh1,
    unsigned short* __restrict__ sl0, unsigned short* __restrict__ sl1,
    float* __restrict__ mfp0, float* __restrict__ mfp1,
    float* __restrict__ out, unsigned* __restrict__ barArr,
    unsigned* __restrict__ barGo) {
  int tid = threadIdx.x;
  unsigned ep = 0;

  if (blockIdx.x < NH) {
    // ================= H role =================
    __shared__ float hx[2][64][4];
    __shared__ unsigned lds_pk[32][16];    // packed (hi | lo<<16) h-tile
    int it = blockIdx.x & 63, bh = blockIdx.x >> 6;
    int w = tid >> 6, lane = tid & 63;
    int tw = w & 1, kh = w >> 1;
    int b0 = bh * 32 + tw * 16;
    int i0 = it * 16;
    size_t aoff = (size_t)(b0 + (lane & 15)) * KTOT + (lane >> 4) * 8;
    const unsigned short* bh_ = Ghi + (size_t)(i0 + (lane & 15)) * KTOT + (lane >> 4) * 8;
    const unsigned short* bl_ = Glo + (size_t)(i0 + (lane & 15)) * KTOT + (lane >> 4) * 8;

    grid_barrier(barArr, barGo, ++ep);         // wait x_0 seed

    for (int t = 0; t < SEQ; ++t) {
      const unsigned short* ah_ = ((t & 1) ? sh1 : sh0) + aoff;
      const unsigned short* al_ = ((t & 1) ? sl1 : sl0) + aoff;
      unsigned short* snh = (t & 1) ? sh0 : sh1;
      unsigned short* snl = (t & 1) ? sl0 : sl1;

      f32x4 ahh = {0.f,0.f,0.f,0.f}, alh = {0.f,0.f,0.f,0.f}, ahl = {0.f,0.f,0.f,0.f};
      int kbase = kh * 1792;
      #pragma unroll 4
      for (int kk = 0; kk < 56; ++kk) {
        int k = kbase + kk * 32;
        union { u64 q[2]; short8v v; } avh, avl;
        avh.q[0] = ald(ah_ + k);  avh.q[1] = ald(ah_ + k + 4);
        avl.q[0] = ald(al_ + k);  avl.q[1] = ald(al_ + k + 4);
        short8v bvh = *(const short8v*)(bh_ + k);
        short8v bvl = *(const short8v*)(bl_ + k);
        ahh = __builtin_amdgcn_mfma_f32_16x16x32_bf16(avh.v, bvh, ahh, 0, 0, 0);
        alh = __builtin_amdgcn_mfma_f32_16x16x32_bf16(avl.v, bvh, alh, 0, 0, 0);
        ahl = __builtin_amdgcn_mfma_f32_16x16x32_bf16(avh.v, bvl, ahl, 0, 0, 0);
      }
      f32x4 acc = ahh + alh + ahl;
      if (kh == 1) {
        *(f32x4*)&hx[tw][lane][0] = acc;
      }
      __syncthreads();
      if (kh == 0) {
        f32x4 o4 = *(const f32x4*)&hx[tw][lane][0];
        #pragma unroll
        for (int r = 0; r < 4; ++r) {
          float v = acc[r] + o4[r];
          float hv = tanhf(v);
          int bl = tw * 16 + (lane >> 4) * 4 + r;      // local row 0..31
          int b = bh * 32 + bl;
          int i = i0 + (lane & 15);
          unsigned short hi = f2bf(hv);
          unsigned short lo = f2bf(hv - bf2f(hi));
          lds_pk[bl][lane & 15] = (unsigned)hi | ((unsigned)lo << 16);
          __builtin_nontemporal_store(hv, &out[((size_t)b * SEQ + t) * HID + i]);
        }
      }
      __syncthreads();
      {
        // all 256 threads: coherent mirror stores (4 i's per u64)
        int plane = tid >> 7, row = (tid >> 2) & 31, i4 = (tid & 3) * 4;
        unsigned w0 = lds_pk[row][i4], w1 = lds_pk[row][i4 + 1];
        unsigned w2 = lds_pk[row][i4 + 2], w3 = lds_pk[row][i4 + 3];
        u64 v;
        if (plane == 0)
          v = (u64)(w0 & 0xFFFF) | ((u64)(w1 & 0xFFFF) << 16) |
              ((u64)(w2 & 0xFFFF) << 32) | ((u64)(w3 & 0xFFFF) << 48);
        else
          v = (u64)(w0 >> 16) | ((u64)(w1 >> 16) << 16) |
              ((u64)(w2 >> 16) << 32) | ((u64)(w3 >> 16) << 48);
        int gb = bh * 32 + row;
        unsigned short* dst = (plane ? snl : snh) + (size_t)gb * KTOT + IN_D + i0 + i4;
        ast(dst, v);
      }
      grid_barrier(barArr, barGo, ++ep);
    }
  } else {
    // ================= M role =================
    __shared__ float sst[KTOT];          // [x_t | h | m] fp32
    __shared__ float part[4][MFLAT];     // o-strip partials
    __shared__ float ush[8];
    int b = blockIdx.x - NH;
    int du = tid >> 5, lu = tid & 31;
    const float* exr = Ex + (size_t)du * IN_D;
    const float* ehr = Eh + (size_t)du * HID;
    const float* emr = Em + (size_t)du * MFLAT;
    int os = tid >> 6;                   // o-strip (wave id)
    int p0 = (tid & 63) * 4;
    int dp0 = tid * 8;
    int dr = tid >> 5;
    float bdv[8];
    #pragma unroll
    for (int j = 0; j < 8; ++j) bdv[j] = Bd[(dp0 & 255) + j];

    // seed x_0 hi/lo (coherent)
    if (tid < 128) {
      const float* xr = x + (size_t)b * SEQ * IN_D;
      int k4 = tid * 4;
      unsigned short ph[4], pl[4];
      #pragma unroll
      for (int j = 0; j < 4; ++j) {
        float xv = xr[k4 + j];
        ph[j] = f2bf(xv);
        pl[j] = f2bf(xv - bf2f(ph[j]));
      }
      ast(sh0 + (size_t)b * KTOT + k4, *(u64*)ph);
      ast(sl0 + (size_t)b * KTOT + k4, *(u64*)pl);
    }
    grid_barrier(barArr, barGo, ++ep);

    for (int t = 0; t < SEQ; ++t) {
      const unsigned short* sch = (t & 1) ? sh1 : sh0;
      const unsigned short* scl = (t & 1) ? sl1 : sl0;
      const float* mc = (t & 1) ? mfp1 : mfp0;
      float* mn = (t & 1) ? mfp0 : mfp1;
      unsigned short* snh = (t & 1) ? sh0 : sh1;
      unsigned short* snl = (t & 1) ? sl0 : sl1;

      // stage [x_t | h | m] fp32 to LDS
      const float* xrow = x + ((size_t)b * SEQ + t) * IN_D;
      #pragma unroll
      for (int j = 0; j < 2; ++j) {                       // x: plain cached
        int k = tid + 256 * j;
        sst[k] = xrow[k];
      }
      {                                                   // h: from hi/lo mirror (coherent)
        int k4 = tid * 4;
        u64 vh = ald(sch + (size_t)b * KTOT + IN_D + k4);
        u64 vl = ald(scl + (size_t)b * KTOT + IN_D + k4);
        #pragma unroll
        for (int j = 0; j < 4; ++j)
          sst[IN_D + k4 + j] = bf2f((unsigned short)(vh >> (16 * j))) +
                               bf2f((unsigned short)(vl >> (16 * j)));
      }
      {                                                   // m: own fp32 master (plain)
        const float4* mc4 = (const float4*)(mc + (size_t)b * MFLAT);
        float4* sst4 = (float4*)(sst + IN_D + HID);
        #pragma unroll
        for (int j = 0; j < 2; ++j) {
          int g = tid + 256 * j;
          sst4[g] = mc4[g];
        }
      }
      __syncthreads();

      // u[d] = Ex.x + Eh.h + Em.m  (32 lanes per d)
      float ua = 0.f;
      #pragma unroll 4
      for (int j = 0; j < 16; ++j) { int k = lu + 32 * j; ua += exr[k] * sst[k]; }
      #pragma unroll 4
      for (int j = 0; j < 32; ++j) { int k = lu + 32 * j; ua += ehr[k] * sst[IN_D + k]; }
      #pragma unroll 4
      for (int j = 0; j < 64; ++j) { int k = lu + 32 * j; ua += emr[k] * sst[IN_D + HID + k]; }
      #pragma unroll
      for (int off = 16; off; off >>= 1) ua += __shfl_xor(ua, off);
      if (lu == 0) ush[du] = ua;
      __syncthreads();

      // matvec partials over this wave's o-strip
      float acc[8][4];
      #pragma unroll
      for (int d = 0; d < 8; ++d)
        acc[d][0] = acc[d][1] = acc[d][2] = acc[d][3] = 0.f;
      const float* mbase = sst + IN_D + HID;
      #pragma unroll 4
      for (int oo = 0; oo < 64; ++oo) {
        int o = os * 64 + oo;
        float4 q = *(const float4*)(AdT + (size_t)o * ORD + p0);
        #pragma unroll
        for (int d = 0; d < 8; ++d) {
          float mv = mbase[d * ORD + o];
          acc[d][0] = fmaf(q.x, mv, acc[d][0]);
          acc[d][1] = fmaf(q.y, mv, acc[d][1]);
          acc[d][2] = fmaf(q.z, mv, acc[d][2]);
          acc[d][3] = fmaf(q.w, mv, acc[d][3]);
        }
      }
      #pragma unroll
      for (int d = 0; d < 8; ++d)
        *(float4*)&part[os][d * ORD + p0] =
            make_float4(acc[d][0], acc[d][1], acc[d][2], acc[d][3]);
      __syncthreads();

      // reduce strips + Bd*u; fp32 master (plain) + hi/lo mirrors (coherent)
      float r[8];
      float uv = ush[dr];
      #pragma unroll
      for (int j = 0; j < 8; ++j) r[j] = bdv[j] * uv;
      #pragma unroll
      for (int s = 0; s < 4; ++s) {
        float4 v0 = *(const float4*)&part[s][dp0];
        float4 v1 = *(const float4*)&part[s][dp0 + 4];
        r[0] += v0.x; r[1] += v0.y; r[2] += v0.z; r[3] += v0.w;
        r[4] += v1.x; r[5] += v1.y; r[6] += v1.z; r[7] += v1.w;
      }
      float4* mo4 = (float4*)(mn + (size_t)b * MFLAT + dp0);
      mo4[0] = make_float4(r[0], r[1], r[2], r[3]);
      mo4[1] = make_float4(r[4], r[5], r[6], r[7]);
      unsigned short ph[8], pl[8];
      #pragma unroll
      for (int j = 0; j < 8; ++j) {
        ph[j] = f2bf(r[j]);
        pl[j] = f2bf(r[j] - bf2f(ph[j]));
      }
      size_t moff = (size_t)b * KTOT + IN_D + HID + dp0;
      ast(snh + moff,     ((u64*)ph)[0]);
      ast(snh + moff + 4, ((u64*)ph)[1]);
      ast(snl + moff,     ((u64*)pl)[0]);
      ast(snl + moff + 4, ((u64*)pl)[1]);

      // seed x_{t+1} hi/lo (coherent)
      if (t + 1 < SEQ && tid < 128) {
        const float* xn = x + ((size_t)b * SEQ + t + 1) * IN_D;
        int k4 = tid * 4;
        unsigned short qh[4], ql[4];
        #pragma unroll
        for (int j = 0; j < 4; ++j) {
          float xv = xn[k4 + j];
          qh[j] = f2bf(xv);
          ql[j] = f2bf(xv - bf2f(qh[j]));
        }
        ast(snh + (size_t)b * KTOT + k4, *(u64*)qh);
        ast(snl + (size_t)b * KTOT + k4, *(u64*)ql);
      }
      grid_barrier(barArr, barGo, ++ep);
    }
  }
}

// ---------------- launch ----------------
extern "C" void kernel_launch(void* const* d_in, const int* in_sizes, int n_in,
                              void* d_out, int out_size, void* d_ws, size_t ws_size,
                              hipStream_t stream) {
  const float* x  = (const float*)d_in[0];
  const float* Ex = (const float*)d_in[1];
  const float* Eh = (const float*)d_in[2];
  const float* Em = (const float*)d_in[3];
  const float* Wx = (const float*)d_in[4];
  const float* Wh = (const float*)d_in[5];
  const float* Wm = (const float*)d_in[6];
  float* out = (float*)d_out;
  float* ws = (float*)d_ws;

  float* dAnat = ws;                         // 65536 f
  float* dAdT  = dAnat + 65536;              // 65536 f
  float* dBd   = dAdT + 65536;               // 512 f
  float* dWmB  = dBd + 512;                  // 8192 f
  unsigned short* dGhi = (unsigned short*)(dWmB + 8192);      // 1024*3584 ush
  unsigned short* dGlo = dGhi + (size_t)HID * KTOT;
  unsigned short* sh0  = dGlo + (size_t)HID * KTOT;           // 64*3584 ush each
  unsigned short* sh1  = sh0 + (size_t)B_SZ * KTOT;
  unsigned short* sl0  = sh1 + (size_t)B_SZ * KTOT;
  unsigned short* sl1  = sl0 + (size_t)B_SZ * KTOT;
  float* mfp0 = (float*)(sl1 + (size_t)B_SZ * KTOT);
  float* mfp1 = mfp0 + B_SZ * MFLAT;
  unsigned* barArr = (unsigned*)(mfp1 + B_SZ * MFLAT);        // NBLK*16 u32
  unsigned* barGo  = barArr + NBLK * BAR_STRIDE;              // 1 u32 (+pad)

  static float h_AdT[ORD * ORD];
  static float h_Anat[ORD * ORD];
  static float h_Bd[ORD];
  compute_AB_host(h_AdT, h_Anat, h_Bd);
  hipMemcpyAsync(dAdT,  h_AdT,  sizeof(h_AdT),  hipMemcpyHostToDevice, stream);
  hipMemcpyAsync(dAnat, h_Anat, sizeof(h_Anat), hipMemcpyHostToDevice, stream);
  hipMemcpyAsync(dBd,   h_Bd,   sizeof(h_Bd),   hipMemcpyHostToDevice, stream);

  hipMemsetAsync(sh0, 0, (size_t)B_SZ * KTOT * sizeof(unsigned short), stream);
  hipMemsetAsync(sl0, 0, (size_t)B_SZ * KTOT * sizeof(unsigned short), stream);
  hipMemsetAsync(mfp0, 0, (size_t)B_SZ * MFLAT * sizeof(float), stream);
  hipMemsetAsync(barArr, 0, (NBLK * BAR_STRIDE + 16) * sizeof(unsigned), stream);

  k_wmb<<<dim3(HID), dim3(256), 0, stream>>>(Wm, dBd, dWmB);
  k_gcat<<<dim3(HID), dim3(256), 0, stream>>>(Wx, Wh, Wm, Ex, Eh, Em, dAnat, dWmB, dGhi, dGlo);

  k_persist<<<dim3(NBLK), dim3(256), 0, stream>>>(
      x, Ex, Eh, Em, dGhi, dGlo, dAdT, dBd, sh0, sh1, sl0, sl1,
      mfp0, mfp1, out, barArr, barGo);
}